// Round 5
// baseline (650.492 us; speedup 1.0000x reference)
//
#include <hip/hip_runtime.h>
#include <hip/hip_bf16.h>

#define NNODES 50000
#define NEDGES 1600000
#define NF 128
#define NC 40
#define NLAYERS 3
#define NPB 64                               // nodes per bucket
#define NBUCKETS ((NNODES + NPB - 1) / NPB)  // 782
#define NCHUNK 256                           // edge chunks (blocks) for counting sort
#define CE (NEDGES / NCHUNK)                 // 6250 edges per chunk
#define NSC (NBUCKETS * NCHUNK)              // 200192 count entries
#define SELEMS ((size_t)NNODES * 32)         // 1.6M bf16 per feature strip
#define SELEMS2 ((size_t)NNODES * 16)        // in bf162 units

typedef __attribute__((ext_vector_type(8))) short bf16x8_t;  // 8 bf16 = 4 VGPR
typedef __attribute__((ext_vector_type(4))) float f32x4_t;

// ---------------------------------------------------------------------------
// CSR build: deterministic counting sort by bucket (NO global atomics),
// then per-bucket node sort that also emits row_ptr and 4-byte packed edges
// (bf16(w) << 16 | src).
// ---------------------------------------------------------------------------

__global__ __launch_bounds__(1024) void count_kernel(const int* __restrict__ dst,
                                                     int* __restrict__ counts) {
    __shared__ int hist[NBUCKETS];
    int t = threadIdx.x;
    for (int i = t; i < NBUCKETS; i += 1024) hist[i] = 0;
    __syncthreads();
    int e0 = blockIdx.x * CE;
    for (int e = e0 + t; e < e0 + CE; e += 1024) {
        atomicAdd(&hist[dst[e] >> 6], 1);
    }
    __syncthreads();
    for (int i = t; i < NBUCKETS; i += 1024) {
        counts[i * NCHUNK + blockIdx.x] = hist[i];
    }
}

__global__ __launch_bounds__(1024) void scan1_kernel(const int* __restrict__ in,
                                                     int* __restrict__ out,
                                                     int* __restrict__ blk_sums, int n) {
    __shared__ int s[1024];
    int t = threadIdx.x;
    int i = blockIdx.x * 1024 + t;
    int v = (i < n) ? in[i] : 0;
    s[t] = v;
    __syncthreads();
    for (int off = 1; off < 1024; off <<= 1) {
        int x = (t >= off) ? s[t - off] : 0;
        __syncthreads();
        s[t] += x;
        __syncthreads();
    }
    int incl = s[t];
    if (i < n) out[i] = incl - v;  // exclusive (block-local)
    if (t == 1023) blk_sums[blockIdx.x] = incl;
}

__global__ __launch_bounds__(256) void scan2_kernel(int* __restrict__ blk_sums, int nb) {
    __shared__ int s[256];
    int t = threadIdx.x;
    int v = (t < nb) ? blk_sums[t] : 0;
    s[t] = v;
    __syncthreads();
    for (int off = 1; off < 256; off <<= 1) {
        int x = (t >= off) ? s[t - off] : 0;
        __syncthreads();
        s[t] += x;
        __syncthreads();
    }
    if (t < nb) blk_sums[t] = s[t] - v;  // exclusive
}

__global__ __launch_bounds__(1024) void scan3_kernel(int* __restrict__ out,
                                                     const int* __restrict__ blk_sums, int n) {
    int i = blockIdx.x * 1024 + threadIdx.x;
    if (i < n) out[i] += blk_sums[blockIdx.x];
}

__global__ __launch_bounds__(1024) void scatter2_kernel(const int* __restrict__ src,
                                                        const int* __restrict__ dst,
                                                        const float* __restrict__ w,
                                                        const int* __restrict__ scanned,
                                                        int2* __restrict__ tmp) {
    __shared__ int cur[NBUCKETS];
    int t = threadIdx.x;
    for (int i = t; i < NBUCKETS; i += 1024) {
        cur[i] = scanned[i * NCHUNK + blockIdx.x];
    }
    __syncthreads();
    int e0 = blockIdx.x * CE;
    for (int e = e0 + t; e < e0 + CE; e += 1024) {
        int d = dst[e];
        int p = atomicAdd(&cur[d >> 6], 1);  // LDS atomic
        int2 v;
        v.x = ((d & 63) << 16) | src[e];
        v.y = __float_as_int(w[e]);
        tmp[p] = v;
    }
}

// one block per bucket: node-level histogram + scan in LDS -> final CSR order
// (4-byte packed edges); also writes row_ptr for the bucket's 64 nodes.
__global__ __launch_bounds__(256) void sort2_kernel(const int* __restrict__ scanned,
                                                    const int2* __restrict__ tmp,
                                                    unsigned int* __restrict__ edges4,
                                                    int* __restrict__ row_ptr) {
    __shared__ int hist[NPB];
    __shared__ int cur[NPB];
    int b = blockIdx.x;
    int t = threadIdx.x;
    int estart = scanned[b * NCHUNK];
    int eend = (b == NBUCKETS - 1) ? NEDGES : scanned[(b + 1) * NCHUNK];

    if (t < NPB) hist[t] = 0;
    __syncthreads();
    for (int e = estart + t; e < eend; e += 256) {
        atomicAdd(&hist[tmp[e].x >> 16], 1);  // LDS atomic
    }
    __syncthreads();
    if (t == 0) {
        int run = estart;
#pragma unroll
        for (int i = 0; i < NPB; ++i) {
            int c = hist[i];
            hist[i] = run;  // exclusive start
            run += c;
        }
    }
    __syncthreads();
    int nb0 = b * NPB;
    if (t < NPB) {
        int node = nb0 + t;
        if (node < NNODES) row_ptr[node] = hist[t];
        cur[t] = hist[t];
    }
    if (b == NBUCKETS - 1 && t == 0) row_ptr[NNODES] = NEDGES;
    __syncthreads();
    for (int e = estart + t; e < eend; e += 256) {
        int2 v = tmp[e];
        int loc = v.x >> 16;
        int p = atomicAdd(&cur[loc], 1);  // LDS atomic
        unsigned wb = (unsigned)v.y;
        unsigned r = (wb + 0x7FFFu + ((wb >> 16) & 1u)) >> 16;  // RNE to bf16
        edges4[p] = (r << 16) | (unsigned)(v.x & 0xFFFF);
    }
}

// ---------------------------------------------------------------------------
// fp32 -> bf16 converts. Feature tables are STRIP-MAJOR: tab[s][node][32],
// strip s = feature f >> 5, so each 3.2 MB strip is a contiguous region
// (strips never share a cache line -> per-XCD L2 can hold one whole strip).
// ---------------------------------------------------------------------------

__global__ __launch_bounds__(256) void cvt_kernel(const float2* __restrict__ in,
                                                  __hip_bfloat162* __restrict__ outS,
                                                  int n2) {
    int i = blockIdx.x * 256 + threadIdx.x;
    int stride = gridDim.x * 256;
    for (; i < n2; i += stride) {
        float2 v = in[i];
        __hip_bfloat162 b;
        b.x = __float2bfloat16(v.x);
        b.y = __float2bfloat16(v.y);
        int n = i >> 6;
        int fp = i & 63;                 // float2-pair index within row
        outS[(size_t)(fp >> 4) * SELEMS2 + (size_t)n * 16 + (fp & 15)] = b;
    }
}

__global__ __launch_bounds__(256) void cvtw_kernel(const float* __restrict__ W0,
                                                   const float* __restrict__ Ws,
                                                   __hip_bfloat16* __restrict__ Wtb) {
    int idx = blockIdx.x * 256 + threadIdx.x;  // 0..65535 (4 matrices)
    int m = idx >> 14;
    int oi = idx & 16383;
    int n = oi >> 7;
    int k = oi & 127;
    const float* src = (m == 0) ? W0 : (Ws + (size_t)(m - 1) * NF * NF);
    Wtb[idx] = __float2bfloat16(src[k * NF + n]);
}

// ---------------------------------------------------------------------------
// SpMM, XCD-strip partitioned: blockIdx&7 -> XCD slot; strip = slot>>1.
// Each XCD gathers only its own 3.2 MB strip => L2-resident.
// Wave handles 1 node x 32 features x 2 edges (lane = (esub<<5)|f);
// shfl_xor(32) combines the two edge-halves. Edges are 4-byte packed.
// ---------------------------------------------------------------------------

__global__ __launch_bounds__(256) void spmm_kernel(const int* __restrict__ row_ptr,
                                                   const unsigned int* __restrict__ edges4,
                                                   const __hip_bfloat16* __restrict__ featS,
                                                   __hip_bfloat16* __restrict__ aggS) {
    int wave = threadIdx.x >> 6;
    int lane = threadIdx.x & 63;
    int xslot = blockIdx.x & 7;          // XCD (round-robin dispatch)
    int s = xslot >> 1;                  // feature strip 0..3
    int n = (blockIdx.x >> 3) * 8 + (xslot & 1) * 4 + wave;

    int e0 = __builtin_amdgcn_readfirstlane(row_ptr[n]);
    int e1 = __builtin_amdgcn_readfirstlane(row_ptr[n + 1]);

    int f = lane & 31;
    int esub = lane >> 5;
    const __hip_bfloat16* tab = featS + (size_t)s * SELEMS;

    float acc = 0.f;
    int e = e0;
    for (; e + 7 < e1; e += 8) {
        unsigned u0 = edges4[e + esub];
        unsigned u1 = edges4[e + 2 + esub];
        unsigned u2 = edges4[e + 4 + esub];
        unsigned u3 = edges4[e + 6 + esub];
        float v0 = __bfloat162float(tab[(u0 & 0xFFFFu) * 32 + f]);
        float v1 = __bfloat162float(tab[(u1 & 0xFFFFu) * 32 + f]);
        float v2 = __bfloat162float(tab[(u2 & 0xFFFFu) * 32 + f]);
        float v3 = __bfloat162float(tab[(u3 & 0xFFFFu) * 32 + f]);
        acc += __uint_as_float(u0 & 0xFFFF0000u) * v0;   // bf16<<16 IS the fp32
        acc += __uint_as_float(u1 & 0xFFFF0000u) * v1;
        acc += __uint_as_float(u2 & 0xFFFF0000u) * v2;
        acc += __uint_as_float(u3 & 0xFFFF0000u) * v3;
    }
    for (; e + 1 < e1; e += 2) {
        unsigned u = edges4[e + esub];
        acc += __uint_as_float(u & 0xFFFF0000u) *
               __bfloat162float(tab[(u & 0xFFFFu) * 32 + f]);
    }
    if (e < e1 && esub == 0) {
        unsigned u = edges4[e];
        acc += __uint_as_float(u & 0xFFFF0000u) *
               __bfloat162float(tab[(u & 0xFFFFu) * 32 + f]);
    }
    acc += __shfl_xor(acc, 32, 64);
    if (esub == 0) {
        aggS[(size_t)s * SELEMS + (size_t)n * 32 + f] = __float2bfloat16(acc);
    }
}

// ---------------------------------------------------------------------------
// MFMA bf16 GEMM, no LDS: h[g][:] = relu(A[g][:] @ W + b) (+ h in-place res),
// optional strip-major bf16 table write. A is STRIP-MAJOR (strip = ks).
// C/D layout: col = lane&15, row = (lane>>4)*4 + reg   [m89-verified]
// ---------------------------------------------------------------------------

template <bool RES, bool WB16>
__global__ __launch_bounds__(256) void gemm_mfma_kernel(
    const __hip_bfloat16* __restrict__ A,    // strip-major [4][NNODES][32]
    const __hip_bfloat16* __restrict__ Wt,   // [n][k] bf16
    const float* __restrict__ bias,
    float* h,                                // out (in-out if RES), row-major fp32
    __hip_bfloat16* __restrict__ outb) {     // strip-major bf16 table
    int t = threadIdx.x;
    int wave = t >> 6;
    int lane = t & 63;
    int lr = lane & 15;   // A-row / B-col / D-col within subtile
    int kg = lane >> 4;   // k-group (0..3)
    int row0 = blockIdx.x * 64 + wave * 16;

    int arow = row0 + lr;
    if (arow >= NNODES) arow = NNODES - 1;  // clamp; stores are guarded

    f32x4_t acc[8];
#pragma unroll
    for (int c = 0; c < 8; ++c) acc[c] = (f32x4_t){0.f, 0.f, 0.f, 0.f};

#pragma unroll
    for (int ks = 0; ks < 4; ++ks) {
        bf16x8_t af = *(const bf16x8_t*)&A[(size_t)ks * SELEMS + (size_t)arow * 32 + kg * 8];
#pragma unroll
        for (int c = 0; c < 8; ++c) {
            bf16x8_t bfr = *(const bf16x8_t*)&Wt[(size_t)(c * 16 + lr) * NF + ks * 32 + kg * 8];
            acc[c] = __builtin_amdgcn_mfma_f32_16x16x32_bf16(af, bfr, acc[c], 0, 0, 0);
        }
    }

    float bcol[8];
#pragma unroll
    for (int c = 0; c < 8; ++c) bcol[c] = bias[c * 16 + lr];

#pragma unroll
    for (int j = 0; j < 4; ++j) {
        int g = row0 + kg * 4 + j;
        if (g < NNODES) {
#pragma unroll
            for (int c = 0; c < 8; ++c) {
                int col = c * 16 + lr;
                float v = acc[c][j] + bcol[c];
                v = fmaxf(v, 0.f);
                if (RES) v += h[(size_t)g * NF + col];
                h[(size_t)g * NF + col] = v;
                if (WB16)
                    outb[(size_t)(col >> 5) * SELEMS + (size_t)g * 32 + (col & 31)] =
                        __float2bfloat16(v);
            }
        }
    }
}

// ---------------------------------------------------------------------------
// Head GEMM: out[N,40] = h[N,128] @ Wout + bout (fp32, lW-only LDS)
// ---------------------------------------------------------------------------

__global__ __launch_bounds__(256) void head_kernel(const float* __restrict__ A,
                                                   const float* __restrict__ W,
                                                   const float* __restrict__ bias,
                                                   float* __restrict__ out) {
    __shared__ float lW[NF * NC];  // [k][j]
    int t = threadIdx.x;
    for (int idx = t * 4; idx < NF * NC; idx += 256 * 4) {
        *(float4*)&lW[idx] = *(const float4*)&W[idx];
    }
    __syncthreads();

    int m = t & 7;    // col group: cols m*5..m*5+4
    int rg = t >> 3;  // 0..31
    int row0 = blockIdx.x * 128 + rg * 4;

    float acc[4][5];
#pragma unroll
    for (int r = 0; r < 4; ++r)
#pragma unroll
        for (int j = 0; j < 5; ++j) acc[r][j] = 0.f;

    int gr[4];
#pragma unroll
    for (int r = 0; r < 4; ++r) {
        int g = row0 + r;
        gr[r] = g < NNODES ? g : NNODES - 1;
    }

    for (int k = 0; k < NF; k += 4) {
        float4 a4[4];
#pragma unroll
        for (int r = 0; r < 4; ++r)
            a4[r] = *(const float4*)&A[(size_t)gr[r] * NF + k];
#pragma unroll
        for (int kk = 0; kk < 4; ++kk) {
            float wv[5];
#pragma unroll
            for (int j = 0; j < 5; ++j) wv[j] = lW[(k + kk) * NC + m * 5 + j];
#pragma unroll
            for (int r = 0; r < 4; ++r) {
                float a = (kk == 0) ? a4[r].x : (kk == 1) ? a4[r].y : (kk == 2) ? a4[r].z : a4[r].w;
#pragma unroll
                for (int j = 0; j < 5; ++j) acc[r][j] += a * wv[j];
            }
        }
    }

#pragma unroll
    for (int r = 0; r < 4; ++r) {
        int g = row0 + r;
        if (g < NNODES) {
#pragma unroll
            for (int j = 0; j < 5; ++j) {
                out[(size_t)g * NC + m * 5 + j] = acc[r][j] + bias[m * 5 + j];
            }
        }
    }
}

// ---------------------------------------------------------------------------

extern "C" void kernel_launch(void* const* d_in, const int* in_sizes, int n_in,
                              void* d_out, int out_size, void* d_ws, size_t ws_size,
                              hipStream_t stream) {
    const float* x    = (const float*)d_in[0];
    const int*   esrc = (const int*)d_in[1];
    const int*   edst = (const int*)d_in[2];
    const float* ew   = (const float*)d_in[3];
    const float* W0   = (const float*)d_in[4];
    const float* b0   = (const float*)d_in[5];
    const float* Ws   = (const float*)d_in[6];
    const float* bs   = (const float*)d_in[7];
    const float* Wout = (const float*)d_in[8];
    const float* bout = (const float*)d_in[9];
    float* out = (float*)d_out;

    // workspace carve (256-B aligned); total ~73 MB
    char* p = (char*)d_ws;
    auto alloc = [&](size_t bytes) -> void* {
        void* r = (void*)p;
        p += (bytes + 255) & ~(size_t)255;
        return r;
    };
    int*   row_ptr  = (int*)alloc((size_t)(NNODES + 1) * 4);
    int*   counts   = (int*)alloc((size_t)NSC * 4);
    int*   scanned  = (int*)alloc((size_t)NSC * 4);
    int*   blk_sums = (int*)alloc(256 * 4);
    int2*  tmp      = (int2*)alloc((size_t)NEDGES * 8);
    unsigned int* edges4 = (unsigned int*)alloc((size_t)NEDGES * 4);
    __hip_bfloat16* aggb = (__hip_bfloat16*)alloc((size_t)NNODES * NF * 2);
    float* h        = (float*)alloc((size_t)NNODES * NF * 4);
    __hip_bfloat16* hb   = (__hip_bfloat16*)alloc((size_t)NNODES * NF * 2);
    __hip_bfloat16* Wtb  = (__hip_bfloat16*)alloc((size_t)4 * NF * NF * 2);

    const int nb_sc = (NSC + 1023) / 1024;        // 196
    const int spmm_grid = NNODES;                 // 50000 (8 xcd-slots x 6250)
    const int gemm_grid = (NNODES + 63) / 64;     // 782
    const int head_grid = (NNODES + 127) / 128;   // 391

    // ---- CSR build: counting sort by bucket, then per-bucket node sort ----
    count_kernel<<<NCHUNK, 1024, 0, stream>>>(edst, counts);
    scan1_kernel<<<nb_sc, 1024, 0, stream>>>(counts, scanned, blk_sums, NSC);
    scan2_kernel<<<1, 256, 0, stream>>>(blk_sums, nb_sc);
    scan3_kernel<<<nb_sc, 1024, 0, stream>>>(scanned, blk_sums, NSC);
    scatter2_kernel<<<NCHUNK, 1024, 0, stream>>>(esrc, edst, ew, scanned, tmp);
    sort2_kernel<<<NBUCKETS, 256, 0, stream>>>(scanned, tmp, edges4, row_ptr);

    // ---- converts: x -> strip-major bf16 table; weights -> bf16 W^T ----
    cvt_kernel<<<2048, 256, 0, stream>>>((const float2*)x, (__hip_bfloat162*)hb, NNODES * 64);
    cvtw_kernel<<<256, 256, 0, stream>>>(W0, Ws, Wtb);

    // ---- layer 0: h = relu(spmm(xb) @ W0 + b0); emit bf16 table ----
    spmm_kernel<<<spmm_grid, 256, 0, stream>>>(row_ptr, edges4, hb, aggb);
    gemm_mfma_kernel<false, true>
        <<<gemm_grid, 256, 0, stream>>>(aggb, Wtb, b0, h, hb);

    // ---- residual layers (in-place residual on h) ----
    for (int l = 0; l < NLAYERS; ++l) {
        spmm_kernel<<<spmm_grid, 256, 0, stream>>>(row_ptr, edges4, hb, aggb);
        if (l < NLAYERS - 1) {
            gemm_mfma_kernel<true, true>
                <<<gemm_grid, 256, 0, stream>>>(aggb, Wtb + (size_t)(l + 1) * NF * NF,
                                                bs + (size_t)l * NF, h, hb);
        } else {
            gemm_mfma_kernel<true, false>
                <<<gemm_grid, 256, 0, stream>>>(aggb, Wtb + (size_t)(l + 1) * NF * NF,
                                                bs + (size_t)l * NF, h, nullptr);
        }
    }

    // ---- output head ----
    head_kernel<<<head_grid, 256, 0, stream>>>(h, Wout, bout, out);
}

// Round 7
// 589.321 us; speedup vs baseline: 1.1038x; 1.1038x over previous
//
#include <hip/hip_runtime.h>
#include <hip/hip_bf16.h>

#define NNODES 50000
#define NEDGES 1600000
#define NF 128
#define NC 40
#define NLAYERS 3
#define NPB 64                               // nodes per bucket
#define NBUCKETS ((NNODES + NPB - 1) / NPB)  // 782
#define NCHUNK 256                           // edge chunks (blocks) for counting sort
#define CE (NEDGES / NCHUNK)                 // 6250 edges per chunk
#define NSC (NBUCKETS * NCHUNK)              // 200192 count entries
#define SELEMS ((size_t)NNODES * 32)         // 1.6M bf16 per feature strip
#define SELEMS2 ((size_t)NNODES * 16)        // in bf162 units

typedef __attribute__((ext_vector_type(8))) short bf16x8_t;  // 8 bf16 = 4 VGPR
typedef __attribute__((ext_vector_type(4))) float f32x4_t;

// ---------------------------------------------------------------------------
// CSR build: deterministic counting sort by bucket (NO global atomics),
// then per-bucket node sort that also emits row_ptr and 4-byte packed edges
// (bf16(w) << 16 | src).
// ---------------------------------------------------------------------------

__global__ __launch_bounds__(1024) void count_kernel(const int* __restrict__ dst,
                                                     int* __restrict__ counts) {
    __shared__ int hist[NBUCKETS];
    int t = threadIdx.x;
    for (int i = t; i < NBUCKETS; i += 1024) hist[i] = 0;
    __syncthreads();
    int e0 = blockIdx.x * CE;
    for (int e = e0 + t; e < e0 + CE; e += 1024) {
        atomicAdd(&hist[dst[e] >> 6], 1);
    }
    __syncthreads();
    for (int i = t; i < NBUCKETS; i += 1024) {
        counts[i * NCHUNK + blockIdx.x] = hist[i];
    }
}

__global__ __launch_bounds__(1024) void scan1_kernel(const int* __restrict__ in,
                                                     int* __restrict__ out,
                                                     int* __restrict__ blk_sums, int n) {
    __shared__ int s[1024];
    int t = threadIdx.x;
    int i = blockIdx.x * 1024 + t;
    int v = (i < n) ? in[i] : 0;
    s[t] = v;
    __syncthreads();
    for (int off = 1; off < 1024; off <<= 1) {
        int x = (t >= off) ? s[t - off] : 0;
        __syncthreads();
        s[t] += x;
        __syncthreads();
    }
    int incl = s[t];
    if (i < n) out[i] = incl - v;  // exclusive (block-local)
    if (t == 1023) blk_sums[blockIdx.x] = incl;
}

__global__ __launch_bounds__(256) void scan2_kernel(int* __restrict__ blk_sums, int nb) {
    __shared__ int s[256];
    int t = threadIdx.x;
    int v = (t < nb) ? blk_sums[t] : 0;
    s[t] = v;
    __syncthreads();
    for (int off = 1; off < 256; off <<= 1) {
        int x = (t >= off) ? s[t - off] : 0;
        __syncthreads();
        s[t] += x;
        __syncthreads();
    }
    if (t < nb) blk_sums[t] = s[t] - v;  // exclusive
}

__global__ __launch_bounds__(1024) void scan3_kernel(int* __restrict__ out,
                                                     const int* __restrict__ blk_sums, int n) {
    int i = blockIdx.x * 1024 + threadIdx.x;
    if (i < n) out[i] += blk_sums[blockIdx.x];
}

__global__ __launch_bounds__(1024) void scatter2_kernel(const int* __restrict__ src,
                                                        const int* __restrict__ dst,
                                                        const float* __restrict__ w,
                                                        const int* __restrict__ scanned,
                                                        int2* __restrict__ tmp) {
    __shared__ int cur[NBUCKETS];
    int t = threadIdx.x;
    for (int i = t; i < NBUCKETS; i += 1024) {
        cur[i] = scanned[i * NCHUNK + blockIdx.x];
    }
    __syncthreads();
    int e0 = blockIdx.x * CE;
    for (int e = e0 + t; e < e0 + CE; e += 1024) {
        int d = dst[e];
        int p = atomicAdd(&cur[d >> 6], 1);  // LDS atomic
        int2 v;
        v.x = ((d & 63) << 16) | src[e];
        v.y = __float_as_int(w[e]);
        tmp[p] = v;
    }
}

// one block per bucket: node-level histogram + scan in LDS -> final CSR order
// (4-byte packed edges); also writes row_ptr for the bucket's 64 nodes.
__global__ __launch_bounds__(256) void sort2_kernel(const int* __restrict__ scanned,
                                                    const int2* __restrict__ tmp,
                                                    unsigned int* __restrict__ edges4,
                                                    int* __restrict__ row_ptr) {
    __shared__ int hist[NPB];
    __shared__ int cur[NPB];
    int b = blockIdx.x;
    int t = threadIdx.x;
    int estart = scanned[b * NCHUNK];
    int eend = (b == NBUCKETS - 1) ? NEDGES : scanned[(b + 1) * NCHUNK];

    if (t < NPB) hist[t] = 0;
    __syncthreads();
    for (int e = estart + t; e < eend; e += 256) {
        atomicAdd(&hist[tmp[e].x >> 16], 1);  // LDS atomic
    }
    __syncthreads();
    if (t == 0) {
        int run = estart;
#pragma unroll
        for (int i = 0; i < NPB; ++i) {
            int c = hist[i];
            hist[i] = run;  // exclusive start
            run += c;
        }
    }
    __syncthreads();
    int nb0 = b * NPB;
    if (t < NPB) {
        int node = nb0 + t;
        if (node < NNODES) row_ptr[node] = hist[t];
        cur[t] = hist[t];
    }
    if (b == NBUCKETS - 1 && t == 0) row_ptr[NNODES] = NEDGES;
    __syncthreads();
    for (int e = estart + t; e < eend; e += 256) {
        int2 v = tmp[e];
        int loc = v.x >> 16;
        int p = atomicAdd(&cur[loc], 1);  // LDS atomic
        unsigned wb = (unsigned)v.y;
        unsigned r = (wb + 0x7FFFu + ((wb >> 16) & 1u)) >> 16;  // RNE to bf16
        edges4[p] = (r << 16) | (unsigned)(v.x & 0xFFFF);
    }
}

// ---------------------------------------------------------------------------
// fp32 -> bf16 converts. Feature tables are STRIP-MAJOR: tab[s][node][32],
// strip s = feature f >> 5, so each 3.2 MB strip is a contiguous region
// (strips never share a cache line -> per-XCD L2 can hold one whole strip).
// ---------------------------------------------------------------------------

__global__ __launch_bounds__(256) void cvt_kernel(const float2* __restrict__ in,
                                                  __hip_bfloat162* __restrict__ outS,
                                                  int n2) {
    int i = blockIdx.x * 256 + threadIdx.x;
    int stride = gridDim.x * 256;
    for (; i < n2; i += stride) {
        float2 v = in[i];
        __hip_bfloat162 b;
        b.x = __float2bfloat16(v.x);
        b.y = __float2bfloat16(v.y);
        int n = i >> 6;
        int fp = i & 63;                 // float2-pair index within row
        outS[(size_t)(fp >> 4) * SELEMS2 + (size_t)n * 16 + (fp & 15)] = b;
    }
}

__global__ __launch_bounds__(256) void cvtw_kernel(const float* __restrict__ W0,
                                                   const float* __restrict__ Ws,
                                                   __hip_bfloat16* __restrict__ Wtb) {
    int idx = blockIdx.x * 256 + threadIdx.x;  // 0..65535 (4 matrices)
    int m = idx >> 14;
    int oi = idx & 16383;
    int n = oi >> 7;
    int k = oi & 127;
    const float* src = (m == 0) ? W0 : (Ws + (size_t)(m - 1) * NF * NF);
    Wtb[idx] = __float2bfloat16(src[k * NF + n]);
}

// ---------------------------------------------------------------------------
// SpMM, XCD-strip partitioned: blockIdx&7 -> XCD slot; strip = slot>>1.
// Each XCD gathers only its own 3.2 MB strip => L2-resident.
// Wave = 8 edges x 32 features: lane = (eg = lane>>3) edge group, (fq =
// lane&7) feature quad. Each lane gathers 8 B (4 bf16) of its edge's row
// (8 lanes x 8 B = full 64 B row segment); edge words broadcast per group.
// Next edge-word load is software-pipelined over the current gather.
// Tail: u = 0 (w = +0.0, row 0) keeps the body branchless and exact.
// shfl_xor(8/16/32) reduces over edge groups; 8-lane bf16x4 store.
// ---------------------------------------------------------------------------

__global__ __launch_bounds__(256) void spmm_kernel(const int* __restrict__ row_ptr,
                                                   const unsigned int* __restrict__ edges4,
                                                   const __hip_bfloat16* __restrict__ featS,
                                                   __hip_bfloat16* __restrict__ aggS) {
    int wave = threadIdx.x >> 6;
    int lane = threadIdx.x & 63;
    int xslot = blockIdx.x & 7;          // XCD (round-robin dispatch)
    int s = xslot >> 1;                  // feature strip 0..3
    int n = (blockIdx.x >> 3) * 8 + (xslot & 1) * 4 + wave;

    int e0 = __builtin_amdgcn_readfirstlane(row_ptr[n]);
    int e1 = __builtin_amdgcn_readfirstlane(row_ptr[n + 1]);

    int fq = lane & 7;                   // feature quad within strip
    int eg = lane >> 3;                  // edge group 0..7
    const __hip_bfloat16* tab = featS + (size_t)s * SELEMS;

    float a0 = 0.f, a1 = 0.f, a2 = 0.f, a3 = 0.f;

    int e = e0;
    unsigned u = (e + eg < e1) ? edges4[e + eg] : 0u;
    while (e < e1) {
        int enext = e + 8;
        unsigned unext = 0u;
        if (enext + eg < e1) unext = edges4[enext + eg];
        ushort4 v = *(const ushort4*)&tab[(size_t)(u & 0xFFFFu) * 32 + fq * 4];
        float w = __uint_as_float(u & 0xFFFF0000u);  // bf16<<16 IS the fp32
        a0 += w * __uint_as_float((unsigned)v.x << 16);
        a1 += w * __uint_as_float((unsigned)v.y << 16);
        a2 += w * __uint_as_float((unsigned)v.z << 16);
        a3 += w * __uint_as_float((unsigned)v.w << 16);
        u = unext;
        e = enext;
    }

    // reduce across the 8 edge groups
#pragma unroll
    for (int off = 8; off < 64; off <<= 1) {
        a0 += __shfl_xor(a0, off);
        a1 += __shfl_xor(a1, off);
        a2 += __shfl_xor(a2, off);
        a3 += __shfl_xor(a3, off);
    }

    if (eg == 0) {
        __hip_bfloat162 p0, p1;
        p0.x = __float2bfloat16(a0);
        p0.y = __float2bfloat16(a1);
        p1.x = __float2bfloat16(a2);
        p1.y = __float2bfloat16(a3);
        __hip_bfloat162* dst =
            (__hip_bfloat162*)(aggS + (size_t)s * SELEMS + (size_t)n * 32 + fq * 4);
        dst[0] = p0;
        dst[1] = p1;
    }
}

// ---------------------------------------------------------------------------
// MFMA bf16 GEMM, no LDS: h[g][:] = relu(A[g][:] @ W + b) (+ h in-place res),
// optional strip-major bf16 table write. A is STRIP-MAJOR (strip = ks).
// C/D layout: col = lane&15, row = (lane>>4)*4 + reg   [m89-verified]
// ---------------------------------------------------------------------------

template <bool RES, bool WB16>
__global__ __launch_bounds__(256) void gemm_mfma_kernel(
    const __hip_bfloat16* __restrict__ A,    // strip-major [4][NNODES][32]
    const __hip_bfloat16* __restrict__ Wt,   // [n][k] bf16
    const float* __restrict__ bias,
    float* h,                                // out (in-out if RES), row-major fp32
    __hip_bfloat16* __restrict__ outb) {     // strip-major bf16 table
    int t = threadIdx.x;
    int wave = t >> 6;
    int lane = t & 63;
    int lr = lane & 15;   // A-row / B-col / D-col within subtile
    int kg = lane >> 4;   // k-group (0..3)
    int row0 = blockIdx.x * 64 + wave * 16;

    int arow = row0 + lr;
    if (arow >= NNODES) arow = NNODES - 1;  // clamp; stores are guarded

    f32x4_t acc[8];
#pragma unroll
    for (int c = 0; c < 8; ++c) acc[c] = (f32x4_t){0.f, 0.f, 0.f, 0.f};

#pragma unroll
    for (int ks = 0; ks < 4; ++ks) {
        bf16x8_t af = *(const bf16x8_t*)&A[(size_t)ks * SELEMS + (size_t)arow * 32 + kg * 8];
#pragma unroll
        for (int c = 0; c < 8; ++c) {
            bf16x8_t bfr = *(const bf16x8_t*)&Wt[(size_t)(c * 16 + lr) * NF + ks * 32 + kg * 8];
            acc[c] = __builtin_amdgcn_mfma_f32_16x16x32_bf16(af, bfr, acc[c], 0, 0, 0);
        }
    }

    float bcol[8];
#pragma unroll
    for (int c = 0; c < 8; ++c) bcol[c] = bias[c * 16 + lr];

#pragma unroll
    for (int j = 0; j < 4; ++j) {
        int g = row0 + kg * 4 + j;
        if (g < NNODES) {
#pragma unroll
            for (int c = 0; c < 8; ++c) {
                int col = c * 16 + lr;
                float v = acc[c][j] + bcol[c];
                v = fmaxf(v, 0.f);
                if (RES) v += h[(size_t)g * NF + col];
                h[(size_t)g * NF + col] = v;
                if (WB16)
                    outb[(size_t)(col >> 5) * SELEMS + (size_t)g * 32 + (col & 31)] =
                        __float2bfloat16(v);
            }
        }
    }
}

// ---------------------------------------------------------------------------
// Head GEMM: out[N,40] = h[N,128] @ Wout + bout (fp32, lW-only LDS)
// ---------------------------------------------------------------------------

__global__ __launch_bounds__(256) void head_kernel(const float* __restrict__ A,
                                                   const float* __restrict__ W,
                                                   const float* __restrict__ bias,
                                                   float* __restrict__ out) {
    __shared__ float lW[NF * NC];  // [k][j]
    int t = threadIdx.x;
    for (int idx = t * 4; idx < NF * NC; idx += 256 * 4) {
        *(float4*)&lW[idx] = *(const float4*)&W[idx];
    }
    __syncthreads();

    int m = t & 7;    // col group: cols m*5..m*5+4
    int rg = t >> 3;  // 0..31
    int row0 = blockIdx.x * 128 + rg * 4;

    float acc[4][5];
#pragma unroll
    for (int r = 0; r < 4; ++r)
#pragma unroll
        for (int j = 0; j < 5; ++j) acc[r][j] = 0.f;

    int gr[4];
#pragma unroll
    for (int r = 0; r < 4; ++r) {
        int g = row0 + r;
        gr[r] = g < NNODES ? g : NNODES - 1;
    }

    for (int k = 0; k < NF; k += 4) {
        float4 a4[4];
#pragma unroll
        for (int r = 0; r < 4; ++r)
            a4[r] = *(const float4*)&A[(size_t)gr[r] * NF + k];
#pragma unroll
        for (int kk = 0; kk < 4; ++kk) {
            float wv[5];
#pragma unroll
            for (int j = 0; j < 5; ++j) wv[j] = lW[(k + kk) * NC + m * 5 + j];
#pragma unroll
            for (int r = 0; r < 4; ++r) {
                float a = (kk == 0) ? a4[r].x : (kk == 1) ? a4[r].y : (kk == 2) ? a4[r].z : a4[r].w;
#pragma unroll
                for (int j = 0; j < 5; ++j) acc[r][j] += a * wv[j];
            }
        }
    }

#pragma unroll
    for (int r = 0; r < 4; ++r) {
        int g = row0 + r;
        if (g < NNODES) {
#pragma unroll
            for (int j = 0; j < 5; ++j) {
                out[(size_t)g * NC + m * 5 + j] = acc[r][j] + bias[m * 5 + j];
            }
        }
    }
}

// ---------------------------------------------------------------------------

extern "C" void kernel_launch(void* const* d_in, const int* in_sizes, int n_in,
                              void* d_out, int out_size, void* d_ws, size_t ws_size,
                              hipStream_t stream) {
    const float* x    = (const float*)d_in[0];
    const int*   esrc = (const int*)d_in[1];
    const int*   edst = (const int*)d_in[2];
    const float* ew   = (const float*)d_in[3];
    const float* W0   = (const float*)d_in[4];
    const float* b0   = (const float*)d_in[5];
    const float* Ws   = (const float*)d_in[6];
    const float* bs   = (const float*)d_in[7];
    const float* Wout = (const float*)d_in[8];
    const float* bout = (const float*)d_in[9];
    float* out = (float*)d_out;

    // workspace carve (256-B aligned); total ~73 MB
    char* p = (char*)d_ws;
    auto alloc = [&](size_t bytes) -> void* {
        void* r = (void*)p;
        p += (bytes + 255) & ~(size_t)255;
        return r;
    };
    int*   row_ptr  = (int*)alloc((size_t)(NNODES + 1) * 4);
    int*   counts   = (int*)alloc((size_t)NSC * 4);
    int*   scanned  = (int*)alloc((size_t)NSC * 4);
    int*   blk_sums = (int*)alloc(256 * 4);
    int2*  tmp      = (int2*)alloc((size_t)NEDGES * 8);
    unsigned int* edges4 = (unsigned int*)alloc((size_t)NEDGES * 4);
    __hip_bfloat16* aggb = (__hip_bfloat16*)alloc((size_t)NNODES * NF * 2);
    float* h        = (float*)alloc((size_t)NNODES * NF * 4);
    __hip_bfloat16* hb   = (__hip_bfloat16*)alloc((size_t)NNODES * NF * 2);
    __hip_bfloat16* Wtb  = (__hip_bfloat16*)alloc((size_t)4 * NF * NF * 2);

    const int nb_sc = (NSC + 1023) / 1024;        // 196
    const int spmm_grid = NNODES;                 // 50000 (8 xcd-slots x 6250)
    const int gemm_grid = (NNODES + 63) / 64;     // 782
    const int head_grid = (NNODES + 127) / 128;   // 391

    // ---- CSR build: counting sort by bucket, then per-bucket node sort ----
    count_kernel<<<NCHUNK, 1024, 0, stream>>>(edst, counts);
    scan1_kernel<<<nb_sc, 1024, 0, stream>>>(counts, scanned, blk_sums, NSC);
    scan2_kernel<<<1, 256, 0, stream>>>(blk_sums, nb_sc);
    scan3_kernel<<<nb_sc, 1024, 0, stream>>>(scanned, blk_sums, NSC);
    scatter2_kernel<<<NCHUNK, 1024, 0, stream>>>(esrc, edst, ew, scanned, tmp);
    sort2_kernel<<<NBUCKETS, 256, 0, stream>>>(scanned, tmp, edges4, row_ptr);

    // ---- converts: x -> strip-major bf16 table; weights -> bf16 W^T ----
    cvt_kernel<<<2048, 256, 0, stream>>>((const float2*)x, (__hip_bfloat162*)hb, NNODES * 64);
    cvtw_kernel<<<256, 256, 0, stream>>>(W0, Ws, Wtb);

    // ---- layer 0: h = relu(spmm(xb) @ W0 + b0); emit bf16 table ----
    spmm_kernel<<<spmm_grid, 256, 0, stream>>>(row_ptr, edges4, hb, aggb);
    gemm_mfma_kernel<false, true>
        <<<gemm_grid, 256, 0, stream>>>(aggb, Wtb, b0, h, hb);

    // ---- residual layers (in-place residual on h) ----
    for (int l = 0; l < NLAYERS; ++l) {
        spmm_kernel<<<spmm_grid, 256, 0, stream>>>(row_ptr, edges4, hb, aggb);
        if (l < NLAYERS - 1) {
            gemm_mfma_kernel<true, true>
                <<<gemm_grid, 256, 0, stream>>>(aggb, Wtb + (size_t)(l + 1) * NF * NF,
                                                bs + (size_t)l * NF, h, hb);
        } else {
            gemm_mfma_kernel<true, false>
                <<<gemm_grid, 256, 0, stream>>>(aggb, Wtb + (size_t)(l + 1) * NF * NF,
                                                bs + (size_t)l * NF, h, nullptr);
        }
    }

    // ---- output head ----
    head_kernel<<<head_grid, 256, 0, stream>>>(h, Wout, bout, out);
}

// Round 8
// 508.912 us; speedup vs baseline: 1.2782x; 1.1580x over previous
//
#include <hip/hip_runtime.h>
#include <hip/hip_bf16.h>

#define NNODES 50000
#define NEDGES 1600000
#define NF 128
#define NC 40
#define NLAYERS 3
#define NPB 64                               // nodes per bucket
#define NBUCKETS ((NNODES + NPB - 1) / NPB)  // 782
#define NCHUNK 256                           // edge chunks (blocks) for counting sort
#define CE (NEDGES / NCHUNK)                 // 6250 edges per chunk
#define NSC (NBUCKETS * NCHUNK)              // 200192 count entries
#define SELEMS ((size_t)NNODES * 32)         // 1.6M bf16 per feature strip
#define SELEMS2 ((size_t)NNODES * 16)        // in bf162 units

typedef __attribute__((ext_vector_type(8))) short bf16x8_t;  // 8 bf16 = 4 VGPR
typedef __attribute__((ext_vector_type(4))) float f32x4_t;

// ---------------------------------------------------------------------------
// CSR build: deterministic counting sort by bucket (NO global atomics),
// then per-bucket node sort that also emits row_ptr and 4-byte packed edges
// (bf16(w) << 16 | src).
// ---------------------------------------------------------------------------

__global__ __launch_bounds__(1024) void count_kernel(const int* __restrict__ dst,
                                                     int* __restrict__ counts) {
    __shared__ int hist[NBUCKETS];
    int t = threadIdx.x;
    for (int i = t; i < NBUCKETS; i += 1024) hist[i] = 0;
    __syncthreads();
    int e0 = blockIdx.x * CE;
    for (int e = e0 + t; e < e0 + CE; e += 1024) {
        atomicAdd(&hist[dst[e] >> 6], 1);
    }
    __syncthreads();
    for (int i = t; i < NBUCKETS; i += 1024) {
        counts[i * NCHUNK + blockIdx.x] = hist[i];
    }
}

__global__ __launch_bounds__(1024) void scan1_kernel(const int* __restrict__ in,
                                                     int* __restrict__ out,
                                                     int* __restrict__ blk_sums, int n) {
    __shared__ int s[1024];
    int t = threadIdx.x;
    int i = blockIdx.x * 1024 + t;
    int v = (i < n) ? in[i] : 0;
    s[t] = v;
    __syncthreads();
    for (int off = 1; off < 1024; off <<= 1) {
        int x = (t >= off) ? s[t - off] : 0;
        __syncthreads();
        s[t] += x;
        __syncthreads();
    }
    int incl = s[t];
    if (i < n) out[i] = incl - v;  // exclusive (block-local)
    if (t == 1023) blk_sums[blockIdx.x] = incl;
}

__global__ __launch_bounds__(256) void scan2_kernel(int* __restrict__ blk_sums, int nb) {
    __shared__ int s[256];
    int t = threadIdx.x;
    int v = (t < nb) ? blk_sums[t] : 0;
    s[t] = v;
    __syncthreads();
    for (int off = 1; off < 256; off <<= 1) {
        int x = (t >= off) ? s[t - off] : 0;
        __syncthreads();
        s[t] += x;
        __syncthreads();
    }
    if (t < nb) blk_sums[t] = s[t] - v;  // exclusive
}

__global__ __launch_bounds__(1024) void scan3_kernel(int* __restrict__ out,
                                                     const int* __restrict__ blk_sums, int n) {
    int i = blockIdx.x * 1024 + threadIdx.x;
    if (i < n) out[i] += blk_sums[blockIdx.x];
}

__global__ __launch_bounds__(1024) void scatter2_kernel(const int* __restrict__ src,
                                                        const int* __restrict__ dst,
                                                        const float* __restrict__ w,
                                                        const int* __restrict__ scanned,
                                                        int2* __restrict__ tmp) {
    __shared__ int cur[NBUCKETS];
    int t = threadIdx.x;
    for (int i = t; i < NBUCKETS; i += 1024) {
        cur[i] = scanned[i * NCHUNK + blockIdx.x];
    }
    __syncthreads();
    int e0 = blockIdx.x * CE;
    for (int e = e0 + t; e < e0 + CE; e += 1024) {
        int d = dst[e];
        int p = atomicAdd(&cur[d >> 6], 1);  // LDS atomic
        int2 v;
        v.x = ((d & 63) << 16) | src[e];
        v.y = __float_as_int(w[e]);
        tmp[p] = v;
    }
}

// one block per bucket: node-level histogram + scan in LDS -> final CSR order
// (4-byte packed edges); also writes row_ptr for the bucket's 64 nodes.
__global__ __launch_bounds__(256) void sort2_kernel(const int* __restrict__ scanned,
                                                    const int2* __restrict__ tmp,
                                                    unsigned int* __restrict__ edges4,
                                                    int* __restrict__ row_ptr) {
    __shared__ int hist[NPB];
    __shared__ int cur[NPB];
    int b = blockIdx.x;
    int t = threadIdx.x;
    int estart = scanned[b * NCHUNK];
    int eend = (b == NBUCKETS - 1) ? NEDGES : scanned[(b + 1) * NCHUNK];

    if (t < NPB) hist[t] = 0;
    __syncthreads();
    for (int e = estart + t; e < eend; e += 256) {
        atomicAdd(&hist[tmp[e].x >> 16], 1);  // LDS atomic
    }
    __syncthreads();
    if (t == 0) {
        int run = estart;
#pragma unroll
        for (int i = 0; i < NPB; ++i) {
            int c = hist[i];
            hist[i] = run;  // exclusive start
            run += c;
        }
    }
    __syncthreads();
    int nb0 = b * NPB;
    if (t < NPB) {
        int node = nb0 + t;
        if (node < NNODES) row_ptr[node] = hist[t];
        cur[t] = hist[t];
    }
    if (b == NBUCKETS - 1 && t == 0) row_ptr[NNODES] = NEDGES;
    __syncthreads();
    for (int e = estart + t; e < eend; e += 256) {
        int2 v = tmp[e];
        int loc = v.x >> 16;
        int p = atomicAdd(&cur[loc], 1);  // LDS atomic
        unsigned wb = (unsigned)v.y;
        unsigned r = (wb + 0x7FFFu + ((wb >> 16) & 1u)) >> 16;  // RNE to bf16
        edges4[p] = (r << 16) | (unsigned)(v.x & 0xFFFF);
    }
}

// ---------------------------------------------------------------------------
// fp32 -> bf16 converts. Feature tables are STRIP-MAJOR: tab[s][node][32],
// strip s = feature f >> 5, so each 3.2 MB strip is a contiguous region
// (strips never share a cache line -> per-XCD L2 can hold one whole strip).
// ---------------------------------------------------------------------------

__global__ __launch_bounds__(256) void cvt_kernel(const float2* __restrict__ in,
                                                  __hip_bfloat162* __restrict__ outS,
                                                  int n2) {
    int i = blockIdx.x * 256 + threadIdx.x;
    int stride = gridDim.x * 256;
    for (; i < n2; i += stride) {
        float2 v = in[i];
        __hip_bfloat162 b;
        b.x = __float2bfloat16(v.x);
        b.y = __float2bfloat16(v.y);
        int n = i >> 6;
        int fp = i & 63;                 // float2-pair index within row
        outS[(size_t)(fp >> 4) * SELEMS2 + (size_t)n * 16 + (fp & 15)] = b;
    }
}

__global__ __launch_bounds__(256) void cvtw_kernel(const float* __restrict__ W0,
                                                   const float* __restrict__ Ws,
                                                   __hip_bfloat16* __restrict__ Wtb) {
    int idx = blockIdx.x * 256 + threadIdx.x;  // 0..65535 (4 matrices)
    int m = idx >> 14;
    int oi = idx & 16383;
    int n = oi >> 7;
    int k = oi & 127;
    const float* src = (m == 0) ? W0 : (Ws + (size_t)(m - 1) * NF * NF);
    Wtb[idx] = __float2bfloat16(src[k * NF + n]);
}

// ---------------------------------------------------------------------------
// SpMM, XCD-strip partitioned: blockIdx&7 -> XCD slot; strip = slot>>1.
// Each XCD gathers only its own 3.2 MB strip => L2-resident.
// Wave = 8 edges x 32 features, lane = (eg = lane>>3, fq = lane&7); each
// lane gathers 8 B (4 bf16) of its edge's 64-B row.
// MLP batching: 32 edges per loop trip -- issue 4 independent edge-word
// loads, then 4 independent gathers, then 16 FMAs. One L2 round-trip
// exposure per batch instead of four (round-7 was latency-bound at 45%
// VALUBusy). Tail is branchless: u = 0 => w = +0.0, row 0 (safe address).
// shfl_xor(8/16/32) reduces over edge groups; 8-lane bf16x4 store.
// ---------------------------------------------------------------------------

__global__ __launch_bounds__(256) void spmm_kernel(const int* __restrict__ row_ptr,
                                                   const unsigned int* __restrict__ edges4,
                                                   const __hip_bfloat16* __restrict__ featS,
                                                   __hip_bfloat16* __restrict__ aggS) {
    int wave = threadIdx.x >> 6;
    int lane = threadIdx.x & 63;
    int xslot = blockIdx.x & 7;          // XCD (round-robin dispatch)
    int s = xslot >> 1;                  // feature strip 0..3
    int n = (blockIdx.x >> 3) * 8 + (xslot & 1) * 4 + wave;

    int e0 = __builtin_amdgcn_readfirstlane(row_ptr[n]);
    int e1 = __builtin_amdgcn_readfirstlane(row_ptr[n + 1]);

    int fq = lane & 7;                   // feature quad within strip
    int eg = lane >> 3;                  // edge group 0..7
    // tabq[r] = 4 bf16 at features [fq*4, fq*4+4) of strip row r
    const ushort4* tabq = (const ushort4*)(featS + (size_t)s * SELEMS) + fq;

    float a0 = 0.f, a1 = 0.f, a2 = 0.f, a3 = 0.f;

    for (int e = e0; e < e1; e += 32) {
        int ee = e + eg;
        // 4 independent edge-word loads (issued together)
        unsigned u0 = (ee      < e1) ? edges4[ee]      : 0u;
        unsigned u1 = (ee + 8  < e1) ? edges4[ee + 8]  : 0u;
        unsigned u2 = (ee + 16 < e1) ? edges4[ee + 16] : 0u;
        unsigned u3 = (ee + 24 < e1) ? edges4[ee + 24] : 0u;
        // 4 independent gathers (issued together once edge words land)
        ushort4 v0 = tabq[(size_t)(u0 & 0xFFFFu) * 8];
        ushort4 v1 = tabq[(size_t)(u1 & 0xFFFFu) * 8];
        ushort4 v2 = tabq[(size_t)(u2 & 0xFFFFu) * 8];
        ushort4 v3 = tabq[(size_t)(u3 & 0xFFFFu) * 8];
        float w0 = __uint_as_float(u0 & 0xFFFF0000u);  // bf16<<16 IS the fp32
        float w1 = __uint_as_float(u1 & 0xFFFF0000u);
        float w2 = __uint_as_float(u2 & 0xFFFF0000u);
        float w3 = __uint_as_float(u3 & 0xFFFF0000u);
        a0 += w0 * __uint_as_float((unsigned)v0.x << 16);
        a1 += w0 * __uint_as_float((unsigned)v0.y << 16);
        a2 += w0 * __uint_as_float((unsigned)v0.z << 16);
        a3 += w0 * __uint_as_float((unsigned)v0.w << 16);
        a0 += w1 * __uint_as_float((unsigned)v1.x << 16);
        a1 += w1 * __uint_as_float((unsigned)v1.y << 16);
        a2 += w1 * __uint_as_float((unsigned)v1.z << 16);
        a3 += w1 * __uint_as_float((unsigned)v1.w << 16);
        a0 += w2 * __uint_as_float((unsigned)v2.x << 16);
        a1 += w2 * __uint_as_float((unsigned)v2.y << 16);
        a2 += w2 * __uint_as_float((unsigned)v2.z << 16);
        a3 += w2 * __uint_as_float((unsigned)v2.w << 16);
        a0 += w3 * __uint_as_float((unsigned)v3.x << 16);
        a1 += w3 * __uint_as_float((unsigned)v3.y << 16);
        a2 += w3 * __uint_as_float((unsigned)v3.z << 16);
        a3 += w3 * __uint_as_float((unsigned)v3.w << 16);
    }

    // reduce across the 8 edge groups
#pragma unroll
    for (int off = 8; off < 64; off <<= 1) {
        a0 += __shfl_xor(a0, off);
        a1 += __shfl_xor(a1, off);
        a2 += __shfl_xor(a2, off);
        a3 += __shfl_xor(a3, off);
    }

    if (eg == 0) {
        __hip_bfloat162 p0, p1;
        p0.x = __float2bfloat16(a0);
        p0.y = __float2bfloat16(a1);
        p1.x = __float2bfloat16(a2);
        p1.y = __float2bfloat16(a3);
        __hip_bfloat162* dst =
            (__hip_bfloat162*)(aggS + (size_t)s * SELEMS + (size_t)n * 32 + fq * 4);
        dst[0] = p0;
        dst[1] = p1;
    }
}

// ---------------------------------------------------------------------------
// MFMA bf16 GEMM, no LDS: h[g][:] = relu(A[g][:] @ W + b) (+ h in-place res),
// optional strip-major bf16 table write. A is STRIP-MAJOR (strip = ks).
// C/D layout: col = lane&15, row = (lane>>4)*4 + reg   [m89-verified]
// ---------------------------------------------------------------------------

template <bool RES, bool WB16>
__global__ __launch_bounds__(256) void gemm_mfma_kernel(
    const __hip_bfloat16* __restrict__ A,    // strip-major [4][NNODES][32]
    const __hip_bfloat16* __restrict__ Wt,   // [n][k] bf16
    const float* __restrict__ bias,
    float* h,                                // out (in-out if RES), row-major fp32
    __hip_bfloat16* __restrict__ outb) {     // strip-major bf16 table
    int t = threadIdx.x;
    int wave = t >> 6;
    int lane = t & 63;
    int lr = lane & 15;   // A-row / B-col / D-col within subtile
    int kg = lane >> 4;   // k-group (0..3)
    int row0 = blockIdx.x * 64 + wave * 16;

    int arow = row0 + lr;
    if (arow >= NNODES) arow = NNODES - 1;  // clamp; stores are guarded

    f32x4_t acc[8];
#pragma unroll
    for (int c = 0; c < 8; ++c) acc[c] = (f32x4_t){0.f, 0.f, 0.f, 0.f};

#pragma unroll
    for (int ks = 0; ks < 4; ++ks) {
        bf16x8_t af = *(const bf16x8_t*)&A[(size_t)ks * SELEMS + (size_t)arow * 32 + kg * 8];
#pragma unroll
        for (int c = 0; c < 8; ++c) {
            bf16x8_t bfr = *(const bf16x8_t*)&Wt[(size_t)(c * 16 + lr) * NF + ks * 32 + kg * 8];
            acc[c] = __builtin_amdgcn_mfma_f32_16x16x32_bf16(af, bfr, acc[c], 0, 0, 0);
        }
    }

    float bcol[8];
#pragma unroll
    for (int c = 0; c < 8; ++c) bcol[c] = bias[c * 16 + lr];

#pragma unroll
    for (int j = 0; j < 4; ++j) {
        int g = row0 + kg * 4 + j;
        if (g < NNODES) {
#pragma unroll
            for (int c = 0; c < 8; ++c) {
                int col = c * 16 + lr;
                float v = acc[c][j] + bcol[c];
                v = fmaxf(v, 0.f);
                if (RES) v += h[(size_t)g * NF + col];
                h[(size_t)g * NF + col] = v;
                if (WB16)
                    outb[(size_t)(col >> 5) * SELEMS + (size_t)g * 32 + (col & 31)] =
                        __float2bfloat16(v);
            }
        }
    }
}

// ---------------------------------------------------------------------------
// Head GEMM: out[N,40] = h[N,128] @ Wout + bout (fp32, lW-only LDS)
// ---------------------------------------------------------------------------

__global__ __launch_bounds__(256) void head_kernel(const float* __restrict__ A,
                                                   const float* __restrict__ W,
                                                   const float* __restrict__ bias,
                                                   float* __restrict__ out) {
    __shared__ float lW[NF * NC];  // [k][j]
    int t = threadIdx.x;
    for (int idx = t * 4; idx < NF * NC; idx += 256 * 4) {
        *(float4*)&lW[idx] = *(const float4*)&W[idx];
    }
    __syncthreads();

    int m = t & 7;    // col group: cols m*5..m*5+4
    int rg = t >> 3;  // 0..31
    int row0 = blockIdx.x * 128 + rg * 4;

    float acc[4][5];
#pragma unroll
    for (int r = 0; r < 4; ++r)
#pragma unroll
        for (int j = 0; j < 5; ++j) acc[r][j] = 0.f;

    int gr[4];
#pragma unroll
    for (int r = 0; r < 4; ++r) {
        int g = row0 + r;
        gr[r] = g < NNODES ? g : NNODES - 1;
    }

    for (int k = 0; k < NF; k += 4) {
        float4 a4[4];
#pragma unroll
        for (int r = 0; r < 4; ++r)
            a4[r] = *(const float4*)&A[(size_t)gr[r] * NF + k];
#pragma unroll
        for (int kk = 0; kk < 4; ++kk) {
            float wv[5];
#pragma unroll
            for (int j = 0; j < 5; ++j) wv[j] = lW[(k + kk) * NC + m * 5 + j];
#pragma unroll
            for (int r = 0; r < 4; ++r) {
                float a = (kk == 0) ? a4[r].x : (kk == 1) ? a4[r].y : (kk == 2) ? a4[r].z : a4[r].w;
#pragma unroll
                for (int j = 0; j < 5; ++j) acc[r][j] += a * wv[j];
            }
        }
    }

#pragma unroll
    for (int r = 0; r < 4; ++r) {
        int g = row0 + r;
        if (g < NNODES) {
#pragma unroll
            for (int j = 0; j < 5; ++j) {
                out[(size_t)g * NC + m * 5 + j] = acc[r][j] + bias[m * 5 + j];
            }
        }
    }
}

// ---------------------------------------------------------------------------

extern "C" void kernel_launch(void* const* d_in, const int* in_sizes, int n_in,
                              void* d_out, int out_size, void* d_ws, size_t ws_size,
                              hipStream_t stream) {
    const float* x    = (const float*)d_in[0];
    const int*   esrc = (const int*)d_in[1];
    const int*   edst = (const int*)d_in[2];
    const float* ew   = (const float*)d_in[3];
    const float* W0   = (const float*)d_in[4];
    const float* b0   = (const float*)d_in[5];
    const float* Ws   = (const float*)d_in[6];
    const float* bs   = (const float*)d_in[7];
    const float* Wout = (const float*)d_in[8];
    const float* bout = (const float*)d_in[9];
    float* out = (float*)d_out;

    // workspace carve (256-B aligned); total ~73 MB
    char* p = (char*)d_ws;
    auto alloc = [&](size_t bytes) -> void* {
        void* r = (void*)p;
        p += (bytes + 255) & ~(size_t)255;
        return r;
    };
    int*   row_ptr  = (int*)alloc((size_t)(NNODES + 1) * 4);
    int*   counts   = (int*)alloc((size_t)NSC * 4);
    int*   scanned  = (int*)alloc((size_t)NSC * 4);
    int*   blk_sums = (int*)alloc(256 * 4);
    int2*  tmp      = (int2*)alloc((size_t)NEDGES * 8);
    unsigned int* edges4 = (unsigned int*)alloc((size_t)NEDGES * 4);
    __hip_bfloat16* aggb = (__hip_bfloat16*)alloc((size_t)NNODES * NF * 2);
    float* h        = (float*)alloc((size_t)NNODES * NF * 4);
    __hip_bfloat16* hb   = (__hip_bfloat16*)alloc((size_t)NNODES * NF * 2);
    __hip_bfloat16* Wtb  = (__hip_bfloat16*)alloc((size_t)4 * NF * NF * 2);

    const int nb_sc = (NSC + 1023) / 1024;        // 196
    const int spmm_grid = NNODES;                 // 50000 (8 xcd-slots x 6250)
    const int gemm_grid = (NNODES + 63) / 64;     // 782
    const int head_grid = (NNODES + 127) / 128;   // 391

    // ---- CSR build: counting sort by bucket, then per-bucket node sort ----
    count_kernel<<<NCHUNK, 1024, 0, stream>>>(edst, counts);
    scan1_kernel<<<nb_sc, 1024, 0, stream>>>(counts, scanned, blk_sums, NSC);
    scan2_kernel<<<1, 256, 0, stream>>>(blk_sums, nb_sc);
    scan3_kernel<<<nb_sc, 1024, 0, stream>>>(scanned, blk_sums, NSC);
    scatter2_kernel<<<NCHUNK, 1024, 0, stream>>>(esrc, edst, ew, scanned, tmp);
    sort2_kernel<<<NBUCKETS, 256, 0, stream>>>(scanned, tmp, edges4, row_ptr);

    // ---- converts: x -> strip-major bf16 table; weights -> bf16 W^T ----
    cvt_kernel<<<2048, 256, 0, stream>>>((const float2*)x, (__hip_bfloat162*)hb, NNODES * 64);
    cvtw_kernel<<<256, 256, 0, stream>>>(W0, Ws, Wtb);

    // ---- layer 0: h = relu(spmm(xb) @ W0 + b0); emit bf16 table ----
    spmm_kernel<<<spmm_grid, 256, 0, stream>>>(row_ptr, edges4, hb, aggb);
    gemm_mfma_kernel<false, true>
        <<<gemm_grid, 256, 0, stream>>>(aggb, Wtb, b0, h, hb);

    // ---- residual layers (in-place residual on h) ----
    for (int l = 0; l < NLAYERS; ++l) {
        spmm_kernel<<<spmm_grid, 256, 0, stream>>>(row_ptr, edges4, hb, aggb);
        if (l < NLAYERS - 1) {
            gemm_mfma_kernel<true, true>
                <<<gemm_grid, 256, 0, stream>>>(aggb, Wtb + (size_t)(l + 1) * NF * NF,
                                                bs + (size_t)l * NF, h, hb);
        } else {
            gemm_mfma_kernel<true, false>
                <<<gemm_grid, 256, 0, stream>>>(aggb, Wtb + (size_t)(l + 1) * NF * NF,
                                                bs + (size_t)l * NF, h, nullptr);
        }
    }

    // ---- output head ----
    head_kernel<<<head_grid, 256, 0, stream>>>(h, Wout, bout, out);
}